// Round 1
// baseline (229.243 us; speedup 1.0000x reference)
//
#include <hip/hip_runtime.h>

#define BATCH 32
#define NX 512
#define NY 512
#define XY (NX * NY)

__device__ __forceinline__ void load3(const float* __restrict__ sb, int x, int y, float v[3]) {
    int off = x * NY + y;
    v[0] = sb[off];
    v[1] = sb[off + XY];
    v[2] = sb[off + 2 * XY];
}

__global__ __launch_bounds__(256) void psi11t_kernel(
    const float* __restrict__ s,
    const float* __restrict__ t,
    const float* __restrict__ c0,
    float* __restrict__ out)
{
    int tid = blockIdx.x * blockDim.x + threadIdx.x;
    int bidx = tid / XY;
    int rem  = tid - bidx * XY;
    int x = rem / NY;
    int y = rem - x * NY;

    const float* sb = s + (size_t)bidx * 3 * XY;

    int xm1 = (x == 0)      ? NX - 1 : x - 1;
    int xp1 = (x == NX - 1) ? 0      : x + 1;
    int ym1 = (y == 0)      ? NY - 1 : y - 1;
    int yp1 = (y == NY - 1) ? 0      : y + 1;
    int xm2 = (x < 2)       ? x + NX - 2 : x - 2;
    int xp2 = (x >= NX - 2) ? x - NX + 2 : x + 2;
    int ym2 = (y < 2)       ? y + NY - 2 : y - 2;
    int yp2 = (y >= NY - 2) ? y - NY + 2 : y + 2;

    // 13-site diamond stencil: center, 4 axis-1 (A=x-1,B=x+1,C=y-1,D=y+1),
    // 4 axis-2 (AA,BB,CC,DD), 4 diagonals (AC,AD,BC,BD).
    float sc[3], sA[3], sB[3], sC[3], sD[3];
    float sAA[3], sBB[3], sCC[3], sDD[3];
    float sAC[3], sAD[3], sBC[3], sBD[3];

    load3(sb, x,   y,   sc);
    load3(sb, xm1, y,   sA);
    load3(sb, xp1, y,   sB);
    load3(sb, x,   ym1, sC);
    load3(sb, x,   yp1, sD);
    load3(sb, xm2, y,   sAA);
    load3(sb, xp2, y,   sBB);
    load3(sb, x,   ym2, sCC);
    load3(sb, x,   yp2, sDD);
    load3(sb, xm1, ym1, sAC);
    load3(sb, xm1, yp1, sAD);
    load3(sb, xp1, ym1, sBC);
    load3(sb, xp1, yp1, sBD);

    // b at center and at the 4 neighbors (recomputed, not staged)
    float Fs[3];
    float bc = 0.f, bA = 0.f, bB = 0.f, bC = 0.f, bD = 0.f;
    #pragma unroll
    for (int k = 0; k < 3; k++) {
        float nsum = sA[k] + sB[k] + sC[k] + sD[k];
        Fs[k] = nsum;
        bc += sc[k] * nsum;
        bA += sA[k] * (sAA[k] + sc[k] + sAC[k] + sAD[k]);
        bB += sB[k] * (sc[k]  + sBB[k] + sBC[k] + sBD[k]);
        bC += sC[k] * (sAC[k] + sBC[k] + sCC[k] + sc[k]);
        bD += sD[k] * (sAD[k] + sBD[k] + sc[k]  + sDD[k]);
    }

    // G = Fs*b_center + Fbs, with Fbs = sum of neighbor s * neighbor b
    float G[3];
    #pragma unroll
    for (int k = 0; k < 3; k++) {
        G[k] = Fs[k] * bc + sA[k] * bA + sB[k] * bB + sC[k] * bC + sD[k] * bD;
    }

    // F = s x G  (L[s,r,a] = -eps_{sra}; the two minus signs cancel)
    float coeff = 2.0f * t[0] * c0[0];
    float o0 = (sc[1] * G[2] - sc[2] * G[1]) * coeff;
    float o1 = (sc[2] * G[0] - sc[0] * G[2]) * coeff;
    float o2 = (sc[0] * G[1] - sc[1] * G[0]) * coeff;

    float* ob = out + (size_t)bidx * 3 * XY + x * NY + y;
    ob[0]      = o0;
    ob[XY]     = o1;
    ob[2 * XY] = o2;
}

extern "C" void kernel_launch(void* const* d_in, const int* in_sizes, int n_in,
                              void* d_out, int out_size, void* d_ws, size_t ws_size,
                              hipStream_t stream) {
    const float* s  = (const float*)d_in[0];
    const float* t  = (const float*)d_in[1];
    const float* c0 = (const float*)d_in[2];
    float* out = (float*)d_out;

    int total = BATCH * XY;              // 8,388,608 sites
    int block = 256;
    int grid  = total / block;           // 32768 blocks
    psi11t_kernel<<<grid, block, 0, stream>>>(s, t, c0, out);
}

// Round 2
// 208.452 us; speedup vs baseline: 1.0997x; 1.0997x over previous
//
#include <hip/hip_runtime.h>

#define BATCH 32
#define NX 512
#define NY 512
#define XY (NX * NY)
#define TX 8              // output rows per block
#define ROWS (TX + 4)     // staged rows incl. 2-row halo each side

__global__ __launch_bounds__(256) void psi11t_kernel(
    const float* __restrict__ s,
    const float* __restrict__ t,
    const float* __restrict__ c0,
    float* __restrict__ out)
{
    __shared__ float lds[3][ROWS][NY];   // 3*12*512*4 = 73728 B

    const int tid   = threadIdx.x;
    const int strip = blockIdx.x;        // 64 strips
    const int bidx  = blockIdx.y;        // 32 batches
    const int x0    = strip * TX;
    const float* sb = s + (size_t)bidx * 3 * XY;

    // ---- stage rows x0-2 .. x0+TX+1 (all 3 comps), coalesced float4 ----
    // 3*ROWS*(NY/4) = 4608 float4 => 18 per thread
    for (int f = tid; f < 3 * ROWS * (NY / 4); f += 256) {
        int c   = f / (ROWS * (NY / 4));
        int rem = f - c * (ROWS * (NY / 4));
        int r   = rem / (NY / 4);
        int v   = rem - r * (NY / 4);
        int gx  = x0 + r - 2;
        if (gx < 0)   gx += NX;
        if (gx >= NX) gx -= NX;
        float4 val = *(const float4*)(sb + (size_t)c * XY + (size_t)gx * NY + 4 * v);
        *(float4*)(&lds[c][r][4 * v]) = val;
    }
    __syncthreads();

    const float coeff = 2.0f * t[0] * c0[0];
    const int ty = tid & 127;            // 128 y-groups of 4
    const int rx = tid >> 7;             // 0 or 1: which row of the pair
    const int y0 = ty * 4;

    for (int it = 0; it < TX / 2; ++it) {
        int lr = 2 + it * 2 + rx;        // local row in [2, TX+1]
        int gx = x0 + it * 2 + rx;       // global row

        // register windows (y-overlap reused across the 4 sites)
        float wc[3][8], am[3][6], ap[3][6], a2m[3][4], a2p[3][4];
        #pragma unroll
        for (int c = 0; c < 3; ++c) {
            #pragma unroll
            for (int j = 0; j < 8; ++j)
                wc[c][j] = lds[c][lr][(y0 - 2 + j) & (NY - 1)];
            #pragma unroll
            for (int j = 0; j < 6; ++j) {
                am[c][j] = lds[c][lr - 1][(y0 - 1 + j) & (NY - 1)];
                ap[c][j] = lds[c][lr + 1][(y0 - 1 + j) & (NY - 1)];
            }
            #pragma unroll
            for (int j = 0; j < 4; ++j) {
                a2m[c][j] = lds[c][lr - 2][(y0 + j) & (NY - 1)];
                a2p[c][j] = lds[c][lr + 2][(y0 + j) & (NY - 1)];
            }
        }

        float o[3][4];
        #pragma unroll
        for (int i = 0; i < 4; ++i) {
            float sc[3], sA[3], sB[3], sC[3], sD[3], Fs[3];
            float bc = 0.f, bA = 0.f, bB = 0.f, bC = 0.f, bD = 0.f;
            #pragma unroll
            for (int c = 0; c < 3; ++c) {
                sc[c] = wc[c][2 + i];
                sA[c] = am[c][1 + i];    // x-1
                sB[c] = ap[c][1 + i];    // x+1
                sC[c] = wc[c][1 + i];    // y-1
                sD[c] = wc[c][3 + i];    // y+1
                float sAA = a2m[c][i];       // x-2
                float sBB = a2p[c][i];       // x+2
                float sCC = wc[c][i];        // y-2
                float sDD = wc[c][4 + i];    // y+2
                float sAC = am[c][i];        // x-1,y-1
                float sAD = am[c][2 + i];    // x-1,y+1
                float sBC = ap[c][i];        // x+1,y-1
                float sBD = ap[c][2 + i];    // x+1,y+1
                float nsum = sA[c] + sB[c] + sC[c] + sD[c];
                Fs[c] = nsum;
                bc += sc[c] * nsum;
                bA += sA[c] * (sAA + sc[c] + sAC + sAD);
                bB += sB[c] * (sc[c] + sBB + sBC + sBD);
                bC += sC[c] * (sAC + sBC + sCC + sc[c]);
                bD += sD[c] * (sAD + sBD + sc[c] + sDD);
            }
            float G[3];
            #pragma unroll
            for (int c = 0; c < 3; ++c)
                G[c] = Fs[c] * bc + sA[c] * bA + sB[c] * bB + sC[c] * bC + sD[c] * bD;
            o[0][i] = (sc[1] * G[2] - sc[2] * G[1]) * coeff;
            o[1][i] = (sc[2] * G[0] - sc[0] * G[2]) * coeff;
            o[2][i] = (sc[0] * G[1] - sc[1] * G[0]) * coeff;
        }

        float* ob = out + (size_t)bidx * 3 * XY + (size_t)gx * NY + y0;
        *(float4*)(ob)          = make_float4(o[0][0], o[0][1], o[0][2], o[0][3]);
        *(float4*)(ob + XY)     = make_float4(o[1][0], o[1][1], o[1][2], o[1][3]);
        *(float4*)(ob + 2 * XY) = make_float4(o[2][0], o[2][1], o[2][2], o[2][3]);
    }
}

extern "C" void kernel_launch(void* const* d_in, const int* in_sizes, int n_in,
                              void* d_out, int out_size, void* d_ws, size_t ws_size,
                              hipStream_t stream) {
    const float* s  = (const float*)d_in[0];
    const float* t  = (const float*)d_in[1];
    const float* c0 = (const float*)d_in[2];
    float* out = (float*)d_out;

    dim3 grid(NX / TX, BATCH);   // 64 x 32 = 2048 blocks
    psi11t_kernel<<<grid, 256, 0, stream>>>(s, t, c0, out);
}